// Round 7
// baseline (170.126 us; speedup 1.0000x reference)
//
#include <hip/hip_runtime.h>
#include <hip/hip_bf16.h>
#include <cstdint>

#define K_DIM 768
#define M_DIM 3072
#define BS_TOTAL 16384  // B * S
#define KT 12           // K tiles of 64

typedef __attribute__((ext_vector_type(4))) float f32x4;
typedef __attribute__((ext_vector_type(8))) short bf16x8;
typedef __attribute__((ext_vector_type(4))) unsigned short u16x4;
typedef __attribute__((ext_vector_type(4))) float fv4;

typedef unsigned int u32_g __attribute__((address_space(1)));
typedef unsigned int u32_l __attribute__((address_space(3)));

static __device__ __forceinline__ void async_load16(const void* g, void* l) {
    __builtin_amdgcn_global_load_lds((const u32_g*)g, (u32_l*)l, 16, 0, 0);
}

#define BAR() __builtin_amdgcn_s_barrier()
#define SCHEDB() __builtin_amdgcn_sched_barrier(0)

static __device__ __forceinline__ unsigned short f2bf(float f) {
    unsigned u = __builtin_bit_cast(unsigned, f);
    u += 0x7fffu + ((u >> 16) & 1u);   // RNE
    return (unsigned short)(u >> 16);
}

// Merged prep: blocks [0, M_DIM) densify W rows; rest convert x to bf16.
__global__ void prep_kernel(const float* __restrict__ values,
                            const int* __restrict__ row_offsets,
                            const int* __restrict__ column_indices,
                            unsigned short* __restrict__ Wb,
                            const float* __restrict__ x,
                            unsigned short* __restrict__ xb, int n4) {
    const int b = blockIdx.x;
    const int t = threadIdx.x;
    if (b < M_DIM) {
        const int r = b;
        unsigned int* wrow32 = (unsigned int*)(Wb + (size_t)r * K_DIM);
        for (int i = t; i < K_DIM / 2; i += 256) wrow32[i] = 0u;
        __syncthreads();
        const int start = row_offsets[r], end = row_offsets[r + 1];
        unsigned short* wrow = Wb + (size_t)r * K_DIM;
        for (int i = start + t; i < end; i += 256)
            wrow[column_indices[i]] = f2bf(values[i]);
    } else {
        const int i = (b - M_DIM) * 256 + t;
        if (i < n4) {
            fv4 v = ((const fv4*)x)[i];
            u16x4 o;
            o[0] = f2bf(v[0]); o[1] = f2bf(v[1]); o[2] = f2bf(v[2]); o[3] = f2bf(v[3]);
            ((u16x4*)xb)[i] = o;
        }
    }
}

// ---- Persistent: 256 blocks (1/CU), each 256 rows x 768 cols = 3 subtiles of
// 256x256. Core = round-2's 8-wave/BK=64/8-phase/counted-vmcnt loop (best
// measured). Last K-tile interleaves one quadrant-store group per phase, so the
// epilogue is OLDER than the boundary prologue loads in the VMEM FIFO: the
// boundary vmcnt(4) means "stores + tile0 stages retired, B(t1) flying" —
// identical invariant to round 2, stores hidden under MFMA phases.

#define STAGE_A(buf, t, half)                                                   \
    { _Pragma("unroll") for (int c = 0; c < 2; ++c) {                           \
        const int u = c * 512 + tid;                                            \
        const int row = (half) * 128 + (u >> 3);                                \
        const int gs = (u & 7) ^ (row & 7);                                     \
        async_load16(X + (size_t)(row0 + row) * K_DIM + (t) * 64 + gs * 8,      \
                     &sm[buf][0][row * 64 + (u & 7) * 8]); } }

#define STAGE_B(buf, t, half, cb)                                               \
    { _Pragma("unroll") for (int c = 0; c < 2; ++c) {                           \
        const int u = c * 512 + tid;                                            \
        const int row = (half) * 128 + (u >> 3);                                \
        const int gs = (u & 7) ^ (row & 7);                                     \
        async_load16(W + (size_t)((cb) + row) * K_DIM + (t) * 64 + gs * 8,      \
                     &sm[buf][1][row * 64 + (u & 7) * 8]); } }

#define LDA(buf, mh)                                                            \
    { _Pragma("unroll") for (int mi = 0; mi < 4; ++mi) {                        \
        const int row = wm * 128 + (mh) * 64 + mi * 16 + fr;                    \
        const int sw = (row & 7) << 3;                                          \
        aq[mi][0] = *(const bf16x8*)&sm[buf][0][row * 64 + ((kq * 8) ^ sw)];    \
        aq[mi][1] = *(const bf16x8*)&sm[buf][0][row * 64 + ((32 + kq * 8) ^ sw)]; } }

#define LDB(buf, nh, breg)                                                      \
    { _Pragma("unroll") for (int ni = 0; ni < 2; ++ni) {                        \
        const int row = wn * 64 + (nh) * 32 + ni * 16 + fr;                     \
        const int sw = (row & 7) << 3;                                          \
        breg[ni][0] = *(const bf16x8*)&sm[buf][1][row * 64 + ((kq * 8) ^ sw)];  \
        breg[ni][1] = *(const bf16x8*)&sm[buf][1][row * 64 + ((32 + kq * 8) ^ sw)]; } }

#define MFMA16(mh, nh, breg)                                                    \
    { __builtin_amdgcn_s_setprio(1);                                            \
      _Pragma("unroll") for (int mi = 0; mi < 4; ++mi)                          \
      _Pragma("unroll") for (int ni = 0; ni < 2; ++ni) {                        \
        acc[(mh)*4+mi][(nh)*2+ni] = __builtin_amdgcn_mfma_f32_16x16x32_bf16(    \
            aq[mi][0], breg[ni][0], acc[(mh)*4+mi][(nh)*2+ni], 0, 0, 0);        \
        acc[(mh)*4+mi][(nh)*2+ni] = __builtin_amdgcn_mfma_f32_16x16x32_bf16(    \
            aq[mi][1], breg[ni][1], acc[(mh)*4+mi][(nh)*2+ni], 0, 0, 0); }      \
      __builtin_amdgcn_s_setprio(0); }

// 32 scalar stores per thread: quadrant (mh,nh) of this wave's 128x64 C tile.
#define STORE_Q(mh, nh)                                                         \
    { _Pragma("unroll") for (int mi = 0; mi < 4; ++mi)                          \
      _Pragma("unroll") for (int j = 0; j < 4; ++j) {                           \
        float* op = out + (size_t)(row0 + wm * 128 + (mh) * 64 + mi * 16        \
                                   + kq * 4 + j) * M_DIM                        \
                    + col0 + wn * 64 + (nh) * 32 + fr;                          \
        op[0]  = acc[(mh)*4+mi][(nh)*2+0][j] + bvs[(nh)*2+0];                   \
        op[16] = acc[(mh)*4+mi][(nh)*2+1][j] + bvs[(nh)*2+1]; } }

__global__ __launch_bounds__(512, 2) void gemm_kernel(
    const unsigned short* __restrict__ X,
    const unsigned short* __restrict__ W,
    const float* __restrict__ bias,
    float* __restrict__ out) {
    __shared__ __align__(16) unsigned short sm[2][2][256 * 64];  // 128 KiB

    // 256 blocks: each XCD owns 8 contiguous row-panels (3 MB X, L2-resident)
    const int bid = blockIdx.x;           // 0..255
    const int xcd = bid & 7;
    const int j   = bid >> 3;             // 0..31
    const int by  = xcd * 8 + (j >> 2);   // 0..63
    const int bx  = j & 3;                // 0..3
    const int row0    = by * 256;
    const int colbase = bx * 768;

    const int tid  = threadIdx.x;
    const int lane = tid & 63;
    const int wave = tid >> 6;
    const int wm = wave >> 2;   // 0..1 -> A rows wm*128..+127
    const int wn = wave & 3;    // 0..3 -> B rows wn*64..+63
    const int fr = lane & 15;
    const int kq = lane >> 4;   // 0..3

    bf16x8 aq[4][2], b0[2][2], b1[2][2];

    // bias for all 3 subtiles, loaded once (static indexing after s-unroll)
    float bv3[3][4];
#pragma unroll
    for (int s = 0; s < 3; ++s)
#pragma unroll
        for (int ni = 0; ni < 4; ++ni)
            bv3[s][ni] = bias[colbase + s * 256 + wn * 64 + ni * 16 + fr];

    // initial prologue (s=0): tile 0 fully + B of tile 1
    STAGE_A(0, 0, 0); STAGE_A(0, 0, 1);
    STAGE_B(0, 0, 0, colbase); STAGE_B(0, 0, 1, colbase);
    STAGE_B(1, 1, 0, colbase); STAGE_B(1, 1, 1, colbase);
    asm volatile("s_waitcnt vmcnt(4)" ::: "memory");
    SCHEDB();
    BAR();

#pragma unroll
    for (int s = 0; s < 3; ++s) {
        const int col0 = colbase + s * 256;
        const float* bvs = bv3[s];
        f32x4 acc[8][4] = {};

        for (int t = 0; t < KT - 1; ++t) {
            const int buf = t & 1, nbuf = buf ^ 1;
            // P0: (mh0, nh0)
            LDA(buf, 0);
            LDB(buf, 0, b0);
            STAGE_A(nbuf, t + 1, 0);
            BAR();
            MFMA16(0, 0, b0);
            BAR();
            // P1: (mh0, nh1)
            LDB(buf, 1, b1);
            STAGE_A(nbuf, t + 1, 1);
            BAR();
            MFMA16(0, 1, b1);
            BAR();
            // P2: (mh1, nh1)
            LDA(buf, 1);
            if (t + 2 < KT) STAGE_B(buf, t + 2, 0, col0);
            BAR();
            MFMA16(1, 1, b1);
            BAR();
            // P3: (mh1, nh0)
            if (t + 2 < KT) STAGE_B(buf, t + 2, 1, col0);
            BAR();
            MFMA16(1, 0, b0);
            if (t + 2 < KT)      { asm volatile("s_waitcnt vmcnt(4)" ::: "memory"); }
            else                 { asm volatile("s_waitcnt vmcnt(0)" ::: "memory"); }
            SCHEDB();
            BAR();
        }

        // ---- t = KT-1 (buf = 1): interleave one quadrant-store group per phase.
        // VMEM FIFO here starts EMPTY (t=10 drained vmcnt(0)).
        LDA(1, 0);
        LDB(1, 0, b0);
        BAR();
        MFMA16(0, 0, b0);
        STORE_Q(0, 0);
        BAR();
        LDB(1, 1, b1);
        BAR();
        MFMA16(0, 1, b1);
        STORE_Q(0, 1);
        BAR();
        LDA(1, 1);
        BAR();
        MFMA16(1, 1, b1);
        STORE_Q(1, 1);
        BAR();
        MFMA16(1, 0, b0);
        STORE_Q(1, 0);
        if (s + 1 < 3) {
            // boundary prologue for s+1; stores are older in FIFO, so vmcnt(4)
            // = stores + tile0 stages retired, B(t1) flying (R2 invariant)
            const int cb2 = col0 + 256;
            STAGE_A(0, 0, 0); STAGE_A(0, 0, 1);
            STAGE_B(0, 0, 0, cb2); STAGE_B(0, 0, 1, cb2);
            STAGE_B(1, 1, 0, cb2); STAGE_B(1, 1, 1, cb2);
            asm volatile("s_waitcnt vmcnt(4)" ::: "memory");
            SCHEDB();
        }
        BAR();
    }
}

extern "C" void kernel_launch(void* const* d_in, const int* in_sizes, int n_in,
                              void* d_out, int out_size, void* d_ws, size_t ws_size,
                              hipStream_t stream) {
    const float* values         = (const float*)d_in[0];
    const float* bias           = (const float*)d_in[1];
    const float* x              = (const float*)d_in[2];
    const int*   row_offsets    = (const int*)d_in[4];
    const int*   column_indices = (const int*)d_in[5];

    unsigned short* Wb = (unsigned short*)d_ws;
    unsigned short* Xb = (unsigned short*)((char*)d_ws + (size_t)M_DIM * K_DIM * 2);

    const int n4 = BS_TOTAL * K_DIM / 4;
    const int prep_blocks = M_DIM + (n4 + 255) / 256;
    prep_kernel<<<prep_blocks, 256, 0, stream>>>(values, row_offsets, column_indices,
                                                 Wb, x, Xb, n4);

    gemm_kernel<<<256, 512, 0, stream>>>(Xb, Wb, bias, (float*)d_out);
}

// Round 8
// 104.358 us; speedup vs baseline: 1.6302x; 1.6302x over previous
//
#include <hip/hip_runtime.h>
#include <hip/hip_bf16.h>
#include <cstdint>

#define K_DIM 768
#define M_DIM 3072
#define BS_TOTAL 16384  // B * S
#define KT 12           // K tiles of 64

typedef __attribute__((ext_vector_type(4))) float f32x4;
typedef __attribute__((ext_vector_type(8))) short bf16x8;
typedef __attribute__((ext_vector_type(4))) unsigned short u16x4;
typedef __attribute__((ext_vector_type(4))) float fv4;

typedef unsigned int u32_g __attribute__((address_space(1)));
typedef unsigned int u32_l __attribute__((address_space(3)));

static __device__ __forceinline__ void async_load16(const void* g, void* l) {
    __builtin_amdgcn_global_load_lds((const u32_g*)g, (u32_l*)l, 16, 0, 0);
}

#define BAR() __builtin_amdgcn_s_barrier()
#define SCHEDB() __builtin_amdgcn_sched_barrier(0)

static __device__ __forceinline__ unsigned short f2bf(float f) {
    unsigned u = __builtin_bit_cast(unsigned, f);
    u += 0x7fffu + ((u >> 16) & 1u);   // RNE
    return (unsigned short)(u >> 16);
}

// Merged prep: blocks [0, M_DIM) densify W rows; rest convert x to bf16.
__global__ void prep_kernel(const float* __restrict__ values,
                            const int* __restrict__ row_offsets,
                            const int* __restrict__ column_indices,
                            unsigned short* __restrict__ Wb,
                            const float* __restrict__ x,
                            unsigned short* __restrict__ xb, int n4) {
    const int b = blockIdx.x;
    const int t = threadIdx.x;
    if (b < M_DIM) {
        const int r = b;
        unsigned int* wrow32 = (unsigned int*)(Wb + (size_t)r * K_DIM);
        for (int i = t; i < K_DIM / 2; i += 256) wrow32[i] = 0u;
        __syncthreads();
        const int start = row_offsets[r], end = row_offsets[r + 1];
        unsigned short* wrow = Wb + (size_t)r * K_DIM;
        for (int i = start + t; i < end; i += 256)
            wrow[column_indices[i]] = f2bf(values[i]);
    } else {
        const int i = (b - M_DIM) * 256 + t;
        if (i < n4) {
            fv4 v = ((const fv4*)x)[i];
            u16x4 o;
            o[0] = f2bf(v[0]); o[1] = f2bf(v[1]); o[2] = f2bf(v[2]); o[3] = f2bf(v[3]);
            ((u16x4*)xb)[i] = o;
        }
    }
}

// ---- EXACT round-2 GEMM core (best measured: ~95 us). Only the block->tile
// mapping changed: per XCD, 8 contiguous row-panels (X slice 3 MB, L2-resident)
// with bx OUTER / by INNER, so concurrent working set = X 3 MB + ~4 W col-panels
// (1.5 MB) ~= 4.5 MB ~= L2, instead of sweeping the full 4.7 MB W per row-panel.

#define STAGE_A(buf, t, half)                                                   \
    { _Pragma("unroll") for (int c = 0; c < 2; ++c) {                           \
        const int u = c * 512 + tid;                                            \
        const int row = (half) * 128 + (u >> 3);                                \
        const int gs = (u & 7) ^ (row & 7);                                     \
        async_load16(X + (size_t)(row0 + row) * K_DIM + (t) * 64 + gs * 8,      \
                     &sm[buf][0][row * 64 + (u & 7) * 8]); } }

#define STAGE_B(buf, t, half)                                                   \
    { _Pragma("unroll") for (int c = 0; c < 2; ++c) {                           \
        const int u = c * 512 + tid;                                            \
        const int row = (half) * 128 + (u >> 3);                                \
        const int gs = (u & 7) ^ (row & 7);                                     \
        async_load16(W + (size_t)(col0 + row) * K_DIM + (t) * 64 + gs * 8,      \
                     &sm[buf][1][row * 64 + (u & 7) * 8]); } }

#define LDA(buf, mh)                                                            \
    { _Pragma("unroll") for (int mi = 0; mi < 4; ++mi) {                        \
        const int row = wm * 128 + (mh) * 64 + mi * 16 + fr;                    \
        const int sw = (row & 7) << 3;                                          \
        aq[mi][0] = *(const bf16x8*)&sm[buf][0][row * 64 + ((kq * 8) ^ sw)];    \
        aq[mi][1] = *(const bf16x8*)&sm[buf][0][row * 64 + ((32 + kq * 8) ^ sw)]; } }

#define LDB(buf, nh, breg)                                                      \
    { _Pragma("unroll") for (int ni = 0; ni < 2; ++ni) {                        \
        const int row = wn * 64 + (nh) * 32 + ni * 16 + fr;                     \
        const int sw = (row & 7) << 3;                                          \
        breg[ni][0] = *(const bf16x8*)&sm[buf][1][row * 64 + ((kq * 8) ^ sw)];  \
        breg[ni][1] = *(const bf16x8*)&sm[buf][1][row * 64 + ((32 + kq * 8) ^ sw)]; } }

#define MFMA16(mh, nh, breg)                                                    \
    { __builtin_amdgcn_s_setprio(1);                                            \
      _Pragma("unroll") for (int mi = 0; mi < 4; ++mi)                          \
      _Pragma("unroll") for (int ni = 0; ni < 2; ++ni) {                        \
        acc[(mh)*4+mi][(nh)*2+ni] = __builtin_amdgcn_mfma_f32_16x16x32_bf16(    \
            aq[mi][0], breg[ni][0], acc[(mh)*4+mi][(nh)*2+ni], 0, 0, 0);        \
        acc[(mh)*4+mi][(nh)*2+ni] = __builtin_amdgcn_mfma_f32_16x16x32_bf16(    \
            aq[mi][1], breg[ni][1], acc[(mh)*4+mi][(nh)*2+ni], 0, 0, 0); }      \
      __builtin_amdgcn_s_setprio(0); }

__global__ __launch_bounds__(512, 2) void gemm_kernel(
    const unsigned short* __restrict__ X,
    const unsigned short* __restrict__ W,
    const float* __restrict__ bias,
    float* __restrict__ out) {
    __shared__ __align__(16) unsigned short sm[2][2][256 * 64];  // 128 KiB

    // L2-aware mapping: consecutive blockIdx round-robin across XCDs.
    // Per XCD: j = bid>>3 in 0..95; by = xcd*8 + (j&7)  (8 fixed row-panels),
    // bx = j>>3 (outer, 0..11). Concurrent set: X 3 MB + ~4 W panels 1.5 MB.
    const int bid = blockIdx.x;           // 0..767
    const int xcd = bid & 7;
    const int j   = bid >> 3;             // 0..95
    const int by  = xcd * 8 + (j & 7);    // 0..63
    const int bx  = j >> 3;               // 0..11
    const int row0 = by * 256;
    const int col0 = bx * 256;

    const int tid  = threadIdx.x;
    const int lane = tid & 63;
    const int wave = tid >> 6;
    const int wm = wave >> 2;   // 0..1 -> A rows wm*128..+127
    const int wn = wave & 3;    // 0..3 -> B rows wn*64..+63
    const int fr = lane & 15;
    const int kq = lane >> 4;   // 0..3

    f32x4 acc[8][4] = {};
    bf16x8 aq[4][2], b0[2][2], b1[2][2];

    // prologue: tile 0 fully + B of tile 1 (A of tile 1 staged in t=0 P0/P1)
    STAGE_A(0, 0, 0); STAGE_A(0, 0, 1);
    STAGE_B(0, 0, 0); STAGE_B(0, 0, 1);
    STAGE_B(1, 1, 0); STAGE_B(1, 1, 1);
    asm volatile("s_waitcnt vmcnt(4)" ::: "memory");  // tile 0 complete; B(1) may fly
    SCHEDB();
    BAR();

    for (int t = 0; t < KT; ++t) {
        const int buf = t & 1, nbuf = buf ^ 1;
        // ---- P0: quadrant (mh0, nh0) ----
        LDA(buf, 0);
        LDB(buf, 0, b0);
        if (t + 1 < KT) STAGE_A(nbuf, t + 1, 0);
        BAR();
        MFMA16(0, 0, b0);
        BAR();
        // ---- P1: (mh0, nh1) ----
        LDB(buf, 1, b1);
        if (t + 1 < KT) STAGE_A(nbuf, t + 1, 1);
        BAR();
        MFMA16(0, 1, b1);
        BAR();
        // ---- P2: (mh1, nh1) ----
        LDA(buf, 1);
        if (t + 2 < KT) STAGE_B(buf, t + 2, 0);
        BAR();
        MFMA16(1, 1, b1);
        BAR();
        // ---- P3: (mh1, nh0) ----
        if (t + 2 < KT) STAGE_B(buf, t + 2, 1);
        BAR();
        MFMA16(1, 0, b0);
        // counted wait, once per K-tile; never 0 in steady state
        if (t + 2 < KT)      { asm volatile("s_waitcnt vmcnt(4)" ::: "memory"); SCHEDB(); }
        else if (t + 1 < KT) { asm volatile("s_waitcnt vmcnt(0)" ::: "memory"); SCHEDB(); }
        BAR();
    }

    // epilogue: frag row = kq*4 + j, col = fr (m89-verified C/D layout)
    float bv[4];
#pragma unroll
    for (int ni = 0; ni < 4; ++ni) bv[ni] = bias[col0 + wn * 64 + ni * 16 + fr];

    const int orow0 = row0 + wm * 128 + kq * 4;
#pragma unroll
    for (int mi = 0; mi < 8; ++mi)
#pragma unroll
        for (int jj = 0; jj < 4; ++jj) {
            float* op = out + (size_t)(orow0 + mi * 16 + jj) * M_DIM + col0 + wn * 64 + fr;
#pragma unroll
            for (int ni = 0; ni < 4; ++ni)
                op[ni * 16] = acc[mi][ni][jj] + bv[ni];
        }
}

extern "C" void kernel_launch(void* const* d_in, const int* in_sizes, int n_in,
                              void* d_out, int out_size, void* d_ws, size_t ws_size,
                              hipStream_t stream) {
    const float* values         = (const float*)d_in[0];
    const float* bias           = (const float*)d_in[1];
    const float* x              = (const float*)d_in[2];
    const int*   row_offsets    = (const int*)d_in[4];
    const int*   column_indices = (const int*)d_in[5];

    unsigned short* Wb = (unsigned short*)d_ws;
    unsigned short* Xb = (unsigned short*)((char*)d_ws + (size_t)M_DIM * K_DIM * 2);

    const int n4 = BS_TOTAL * K_DIM / 4;
    const int prep_blocks = M_DIM + (n4 + 255) / 256;
    prep_kernel<<<prep_blocks, 256, 0, stream>>>(values, row_offsets, column_indices,
                                                 Wb, x, Xb, n4);

    const int grid = (BS_TOTAL / 256) * (M_DIM / 256);  // 64 * 12 = 768
    gemm_kernel<<<grid, 512, 0, stream>>>(Xb, Wb, bias, (float*)d_out);
}